// Round 2
// baseline (704.499 us; speedup 1.0000x reference)
//
#include <hip/hip_runtime.h>
#include <hip/hip_bf16.h>
#include <math.h>

typedef unsigned short u16;
typedef __attribute__((ext_vector_type(8))) __bf16 bf16x8;
typedef __attribute__((ext_vector_type(4))) float f32x4;

__device__ inline u16 f2bf(float f) {
  union { float f; unsigned u; } x; x.f = f;
  unsigned r = x.u + 0x7fffu + ((x.u >> 16) & 1u);
  return (u16)(r >> 16);
}

__device__ inline void async16(const void* g, void* l) {
  __builtin_amdgcn_global_load_lds(
      (const __attribute__((address_space(1))) void*)g,
      (__attribute__((address_space(3))) void*)l, 16, 0, 0);
}

// ---------------- cast f32 -> bf16 (vectorized) ----------------
__global__ __launch_bounds__(256) void cast_bf16_kernel(
    const float* __restrict__ in, u16* __restrict__ out, int n4) {
  int i = blockIdx.x * 256 + threadIdx.x;
  if (i >= n4) return;
  float4 v = ((const float4*)in)[i];
  u16 o0 = f2bf(v.x), o1 = f2bf(v.y), o2 = f2bf(v.z), o3 = f2bf(v.w);
  unsigned lo = (unsigned)o0 | ((unsigned)o1 << 16);
  unsigned hi = (unsigned)o2 | ((unsigned)o3 << 16);
  ((uint2*)out)[i] = make_uint2(lo, hi);
}

// ---------------- V transpose: vt[b][d][s] = qkv[b][s][2176+d] ----------------
__global__ __launch_bounds__(256) void vt_kernel(
    const u16* __restrict__ qkv, u16* __restrict__ vt) {
  int idx = blockIdx.x * 256 + threadIdx.x;  // B*128*2048
  int s = idx & 2047;
  int d = (idx >> 11) & 127;
  int b = idx >> 18;
  vt[idx] = qkv[((size_t)b * 2048 + s) * 2304 + 2176 + d];
}

// ---------------- GEMM: C[M][N] = A[M][K] * W[N][K]^T + bias ----------------
template <bool BF16OUT>
__global__ __launch_bounds__(256) void gemm_bt(
    const u16* __restrict__ A, const u16* __restrict__ Bw,
    const float* __restrict__ bias, void* __restrict__ Cout,
    int M, int N, int K) {
  __shared__ u16 As[128 * 64];
  __shared__ u16 Bs[128 * 64];
  const int t = threadIdx.x;
  const int w = t >> 6;
  const int lane = t & 63;
  const int lq = lane >> 4, lr = lane & 15;
  const long brow = (long)blockIdx.y * 128;
  const long bcol = (long)blockIdx.x * 128;
  const int wr = (w >> 1) * 64, wc = (w & 1) * 64;
  f32x4 acc[4][4] = {};

  int rA[4], cA[4];
#pragma unroll
  for (int it = 0; it < 4; ++it) {
    int ci = it * 256 + t;
    rA[it] = ci >> 3;                 // tile row (0..127)
    cA[it] = (ci & 7) ^ (rA[it] & 7); // swizzled source 16B-chunk in row
  }

  for (int kt = 0; kt < K; kt += 64) {
#pragma unroll
    for (int it = 0; it < 4; ++it) {
      const u16* srcA = A + (brow + rA[it]) * (long)K + kt + cA[it] * 8;
      async16(srcA, (char*)As + (it * 256 + w * 64) * 16);
      const u16* srcB = Bw + (bcol + rA[it]) * (long)K + kt + cA[it] * 8;
      async16(srcB, (char*)Bs + (it * 256 + w * 64) * 16);
    }
    __syncthreads();
#pragma unroll
    for (int kb = 0; kb < 2; ++kb) {
      bf16x8 af[4], bfr[4];
#pragma unroll
      for (int m = 0; m < 4; ++m) {
        int row = wr + m * 16 + lr;
        int byte = (row * 128 + kb * 64 + lq * 16) ^ ((row & 7) << 4);
        af[m] = *(const bf16x8*)((const char*)As + byte);
      }
#pragma unroll
      for (int n = 0; n < 4; ++n) {
        int row = wc + n * 16 + lr;
        int byte = (row * 128 + kb * 64 + lq * 16) ^ ((row & 7) << 4);
        bfr[n] = *(const bf16x8*)((const char*)Bs + byte);
      }
#pragma unroll
      for (int m = 0; m < 4; ++m)
#pragma unroll
        for (int n = 0; n < 4; ++n)
          acc[m][n] = __builtin_amdgcn_mfma_f32_16x16x32_bf16(
              af[m], bfr[n], acc[m][n], 0, 0, 0);
    }
    __syncthreads();
  }

#pragma unroll
  for (int m = 0; m < 4; ++m) {
    long row0 = brow + wr + m * 16 + lq * 4;
#pragma unroll
    for (int n = 0; n < 4; ++n) {
      long col = bcol + wc + n * 16 + lr;
      float bv = bias[col];
#pragma unroll
      for (int j = 0; j < 4; ++j) {
        float v = acc[m][n][j] + bv;
        if (BF16OUT)
          ((u16*)Cout)[(row0 + j) * N + col] = f2bf(v);
        else
          ((float*)Cout)[(row0 + j) * N + col] = v;
      }
    }
  }
}

// ---------------- Flash attention (MQA, causal) ----------------
// 4 independent waves per block (no barriers), 16 q-rows per wave,
// KVBLK=64, mask only on the diagonal tile, T13 defer-rescale.
__global__ __launch_bounds__(256) void attn_kernel(
    const u16* __restrict__ qkv, const u16* __restrict__ vt,
    u16* __restrict__ ctx) {
  const int t = threadIdx.x;
  const int w = t >> 6;
  const int lane = t & 63;
  const int lq = lane >> 4, lr = lane & 15;
  const int wid = blockIdx.x * 4 + w;
  const int qt = 127 - (wid & 127);  // heavy tiles dispatched first
  const int h = (wid >> 7) & 15;
  const int b = wid >> 11;
  const int s0 = qt * 16;
  const size_t qb = (size_t)b * 2048 * 2304;

  __shared__ u16 Pl[4][16][72];  // per-wave slice -> no __syncthreads needed

  bf16x8 qf[4];
#pragma unroll
  for (int kc = 0; kc < 4; ++kc)
    qf[kc] = *(const bf16x8*)(qkv + qb + (size_t)(s0 + lr) * 2304 + h * 128 +
                              kc * 32 + lq * 8);

  float mrow[4] = {-INFINITY, -INFINITY, -INFINITY, -INFINITY};
  float lrow[4] = {0.f, 0.f, 0.f, 0.f};
  f32x4 o[8] = {};
  const float scale = 0.08838834764831845f;

  const int nfull = s0 >> 6;  // tiles before the (single) diagonal tile
  const u16* kroot = qkv + qb + 2048 + (size_t)lr * 2304 + lq * 8;
  const u16* vroot = vt + ((size_t)b * 128 + lr) * 2048 + lq * 8;

  for (int j2 = 0; j2 <= nfull; ++j2) {
    const int kvb = j2 * 64;
    const bool diag = (j2 == nfull);

    // ---- QK^T: 16 keys x 4 groups, K=128 in 4 chunks ----
    f32x4 sc[4] = {};
    const u16* kb = kroot + (size_t)kvb * 2304;
#pragma unroll
    for (int g = 0; g < 4; ++g) {
#pragma unroll
      for (int kc = 0; kc < 4; ++kc) {
        bf16x8 kf = *(const bf16x8*)(kb + (size_t)g * 16 * 2304 + kc * 32);
        sc[g] = __builtin_amdgcn_mfma_f32_16x16x32_bf16(qf[kc], kf, sc[g],
                                                        0, 0, 0);
      }
    }

    // ---- online softmax (per row r, reduce across lr lanes) ----
    float vs[4][4];
    float mxr[4];
    bool need = false;
#pragma unroll
    for (int r = 0; r < 4; ++r) {
      const int qi = s0 + lq * 4 + r;
#pragma unroll
      for (int g = 0; g < 4; ++g) {
        float v = sc[g][r] * scale;
        if (diag && (kvb + g * 16 + lr > qi)) v = -INFINITY;
        vs[r][g] = v;
      }
      float mx = fmaxf(fmaxf(vs[r][0], vs[r][1]), fmaxf(vs[r][2], vs[r][3]));
#pragma unroll
      for (int d = 8; d >= 1; d >>= 1) mx = fmaxf(mx, __shfl_xor(mx, d));
      mxr[r] = mx;
      need = need || (mx > mrow[r] + 8.f);
    }
    if (__any(need)) {  // wave-uniform: no divergence
#pragma unroll
      for (int r = 0; r < 4; ++r) {
        float mn = fmaxf(mrow[r], mxr[r]);
        float alpha = __expf(mrow[r] - mn);
        float rs = 0.f;
#pragma unroll
        for (int g = 0; g < 4; ++g) {
          float p = __expf(vs[r][g] - mn);
          rs += p;
          Pl[w][lq * 4 + r][g * 16 + lr] = f2bf(p);
        }
#pragma unroll
        for (int d = 8; d >= 1; d >>= 1) rs += __shfl_xor(rs, d);
        lrow[r] = lrow[r] * alpha + rs;
        mrow[r] = mn;
#pragma unroll
        for (int n = 0; n < 8; ++n) o[n][r] *= alpha;
      }
    } else {  // T13: max didn't grow past THR=8 -> no rescale, keep mrow
#pragma unroll
      for (int r = 0; r < 4; ++r) {
        float rs = 0.f;
#pragma unroll
        for (int g = 0; g < 4; ++g) {
          float p = __expf(vs[r][g] - mrow[r]);
          rs += p;
          Pl[w][lq * 4 + r][g * 16 + lr] = f2bf(p);
        }
#pragma unroll
        for (int d = 8; d >= 1; d >>= 1) rs += __shfl_xor(rs, d);
        lrow[r] += rs;
      }
    }

    // ---- PV: P[16x64] x V[64x128] ----
    bf16x8 pa0 = *(const bf16x8*)(&Pl[w][lr][lq * 8]);
    bf16x8 pa1 = *(const bf16x8*)(&Pl[w][lr][32 + lq * 8]);
    const u16* vb = vroot + kvb;
#pragma unroll
    for (int n = 0; n < 8; ++n) {
      bf16x8 vf0 = *(const bf16x8*)(vb + (size_t)n * 16 * 2048);
      bf16x8 vf1 = *(const bf16x8*)(vb + (size_t)n * 16 * 2048 + 32);
      o[n] = __builtin_amdgcn_mfma_f32_16x16x32_bf16(pa0, vf0, o[n], 0, 0, 0);
      o[n] = __builtin_amdgcn_mfma_f32_16x16x32_bf16(pa1, vf1, o[n], 0, 0, 0);
    }
  }

#pragma unroll
  for (int r = 0; r < 4; ++r) {
    float inv = 1.f / lrow[r];
    size_t rowoff = ((size_t)b * 2048 + s0 + lq * 4 + r) * 2048 + h * 128;
#pragma unroll
    for (int n = 0; n < 8; ++n)
      ctx[rowoff + n * 16 + lr] = f2bf(o[n][r] * inv);
  }
}

extern "C" void kernel_launch(void* const* d_in, const int* in_sizes, int n_in,
                              void* d_out, int out_size, void* d_ws,
                              size_t ws_size, hipStream_t stream) {
  (void)in_sizes; (void)n_in; (void)out_size; (void)ws_size;
  const float* hs = (const float*)d_in[0];
  const float* attn_w = (const float*)d_in[1];
  const float* attn_b = (const float*)d_in[2];
  const float* proj_w = (const float*)d_in[3];
  const float* proj_b = (const float*)d_in[4];
  float* out = (float*)d_out;

  u16* hs_b = (u16*)d_ws;                      // 4096*2048
  u16* aw_b = hs_b + (size_t)4096 * 2048;      // 2304*2048
  u16* pw_b = aw_b + (size_t)2304 * 2048;      // 2048*2048
  u16* qkv_b = pw_b + (size_t)2048 * 2048;     // 4096*2304
  u16* vt_b = qkv_b + (size_t)4096 * 2304;     // 2*128*2048
  u16* ctx_b = vt_b + (size_t)2 * 128 * 2048;  // 4096*2048

  cast_bf16_kernel<<<8192, 256, 0, stream>>>(hs, hs_b, 2097152);
  cast_bf16_kernel<<<4608, 256, 0, stream>>>(attn_w, aw_b, 1179648);
  cast_bf16_kernel<<<4096, 256, 0, stream>>>(proj_w, pw_b, 1048576);

  gemm_bt<true><<<dim3(18, 32), 256, 0, stream>>>(hs_b, aw_b, attn_b, qkv_b,
                                                  4096, 2304, 2048);
  vt_kernel<<<2048, 256, 0, stream>>>(qkv_b, vt_b);
  attn_kernel<<<1024, 256, 0, stream>>>(qkv_b, vt_b, ctx_b);
  gemm_bt<false><<<dim3(16, 32), 256, 0, stream>>>(ctx_b, pw_b, proj_b, out,
                                                   4096, 2048, 2048);
}

// Round 3
// 240.056 us; speedup vs baseline: 2.9347x; 2.9347x over previous
//
#include <hip/hip_runtime.h>
#include <hip/hip_bf16.h>
#include <math.h>

typedef unsigned short u16;
typedef __attribute__((ext_vector_type(8))) __bf16 bf16x8;
typedef __attribute__((ext_vector_type(4))) float f32x4;

__device__ inline u16 f2bf(float f) {
  union { float f; unsigned u; } x; x.f = f;
  unsigned r = x.u + 0x7fffu + ((x.u >> 16) & 1u);
  return (u16)(r >> 16);
}

__device__ inline void async16(const void* g, void* l) {
  __builtin_amdgcn_global_load_lds(
      (const __attribute__((address_space(1))) void*)g,
      (__attribute__((address_space(3))) void*)l, 16, 0, 0);
}

// ---------------- cast f32 -> bf16 (vectorized) ----------------
__global__ __launch_bounds__(256) void cast_bf16_kernel(
    const float* __restrict__ in, u16* __restrict__ out, int n4) {
  int i = blockIdx.x * 256 + threadIdx.x;
  if (i >= n4) return;
  float4 v = ((const float4*)in)[i];
  u16 o0 = f2bf(v.x), o1 = f2bf(v.y), o2 = f2bf(v.z), o3 = f2bf(v.w);
  unsigned lo = (unsigned)o0 | ((unsigned)o1 << 16);
  unsigned hi = (unsigned)o2 | ((unsigned)o3 << 16);
  ((uint2*)out)[i] = make_uint2(lo, hi);
}

// ---------------- V transpose via LDS: vt[b][d][s] = qkv[b][s][2176+d] ------
__global__ __launch_bounds__(256) void vt_kernel(
    const u16* __restrict__ qkv, u16* __restrict__ vt) {
  __shared__ u16 tile[32][136];
  const int t = threadIdx.x;
  const int b = blockIdx.x >> 6;
  const int S0 = (blockIdx.x & 63) * 32;
  const int s_l = t >> 3, dg = t & 7;
  const u16* src = qkv + ((size_t)b * 2048 + S0 + s_l) * 2304 + 2176 + dg * 16;
  *(uint4*)&tile[s_l][dg * 16] = *(const uint4*)src;
  *(uint4*)&tile[s_l][dg * 16 + 8] = *(const uint4*)(src + 8);
  __syncthreads();
  const int d = t >> 1, sh = t & 1;
  u16 buf[16];
#pragma unroll
  for (int j = 0; j < 16; ++j) buf[j] = tile[sh * 16 + j][d];
  u16* dst = vt + ((size_t)b * 128 + d) * 2048 + S0 + sh * 16;
  *(uint4*)dst = *(uint4*)&buf[0];
  *(uint4*)(dst + 8) = *(uint4*)&buf[8];
}

// ---------------- GEMM: C[M][N] = A[M][K] * W[N][K]^T + bias ----------------
template <bool BF16OUT>
__global__ __launch_bounds__(256) void gemm_bt(
    const u16* __restrict__ A, const u16* __restrict__ Bw,
    const float* __restrict__ bias, void* __restrict__ Cout,
    int M, int N, int K) {
  __shared__ u16 As[128 * 64];
  __shared__ u16 Bs[128 * 64];
  const int t = threadIdx.x;
  const int w = t >> 6;
  const int lane = t & 63;
  const int lq = lane >> 4, lr = lane & 15;
  const long brow = (long)blockIdx.y * 128;
  const long bcol = (long)blockIdx.x * 128;
  const int wr = (w >> 1) * 64, wc = (w & 1) * 64;
  f32x4 acc[4][4] = {};

  int rA[4], cA[4];
#pragma unroll
  for (int it = 0; it < 4; ++it) {
    int ci = it * 256 + t;
    rA[it] = ci >> 3;
    cA[it] = (ci & 7) ^ (rA[it] & 7);
  }

  for (int kt = 0; kt < K; kt += 64) {
#pragma unroll
    for (int it = 0; it < 4; ++it) {
      const u16* srcA = A + (brow + rA[it]) * (long)K + kt + cA[it] * 8;
      async16(srcA, (char*)As + (it * 256 + w * 64) * 16);
      const u16* srcB = Bw + (bcol + rA[it]) * (long)K + kt + cA[it] * 8;
      async16(srcB, (char*)Bs + (it * 256 + w * 64) * 16);
    }
    __syncthreads();
#pragma unroll
    for (int kb = 0; kb < 2; ++kb) {
      bf16x8 af[4], bfr[4];
#pragma unroll
      for (int m = 0; m < 4; ++m) {
        int row = wr + m * 16 + lr;
        int byte = (row * 128 + kb * 64 + lq * 16) ^ ((row & 7) << 4);
        af[m] = *(const bf16x8*)((const char*)As + byte);
      }
#pragma unroll
      for (int n = 0; n < 4; ++n) {
        int row = wc + n * 16 + lr;
        int byte = (row * 128 + kb * 64 + lq * 16) ^ ((row & 7) << 4);
        bfr[n] = *(const bf16x8*)((const char*)Bs + byte);
      }
#pragma unroll
      for (int m = 0; m < 4; ++m)
#pragma unroll
        for (int n = 0; n < 4; ++n)
          acc[m][n] = __builtin_amdgcn_mfma_f32_16x16x32_bf16(
              af[m], bfr[n], acc[m][n], 0, 0, 0);
    }
    __syncthreads();
  }

#pragma unroll
  for (int m = 0; m < 4; ++m) {
    long row0 = brow + wr + m * 16 + lq * 4;
#pragma unroll
    for (int n = 0; n < 4; ++n) {
      long col = bcol + wc + n * 16 + lr;
      float bv = bias[col];
#pragma unroll
      for (int j = 0; j < 4; ++j) {
        float v = acc[m][n][j] + bv;
        if (BF16OUT)
          ((u16*)Cout)[(row0 + j) * N + col] = f2bf(v);
        else
          ((float*)Cout)[(row0 + j) * N + col] = v;
      }
    }
  }
}

// ---------------- Flash attention (MQA, causal) ----------------
// Block = 4 waves x 16 q-rows = 64 rows. K/V staged in LDS (double-buffered,
// global_load_lds w/ pre-swizzled source, XOR-swizzled reads). KVBLK=64.
// Mask only in the final (diagonal) tile; T13 defer-rescale.
__global__ __launch_bounds__(256) void attn_kernel(
    const u16* __restrict__ qkv, const u16* __restrict__ vt,
    u16* __restrict__ ctx) {
  __shared__ u16 Kl[2][64 * 128];
  __shared__ u16 Vl[2][128 * 64];
  __shared__ u16 Pl[4][16][72];

  const int t = threadIdx.x;
  const int w = t >> 6;
  const int lane = t & 63;
  const int lq = lane >> 4, lr = lane & 15;
  const int bid = blockIdx.x;
  const int qt = 31 - (bid >> 5);  // all heaviest blocks dispatched first
  const int hb = bid & 31;
  const int h = hb & 15;
  const int b = hb >> 4;
  const int Q0 = qt * 64;
  const int s0w = Q0 + w * 16;
  const size_t qb = (size_t)b * 2048 * 2304;

  // Q fragments (one-time global gather)
  bf16x8 qf[4];
#pragma unroll
  for (int kc = 0; kc < 4; ++kc)
    qf[kc] = *(const bf16x8*)(qkv + qb + (size_t)(s0w + lr) * 2304 + h * 128 +
                              kc * 32 + lq * 8);

  // staging: 16 wave-instrs each for K and V, 4 per wave
  auto stageK = [&](int buf, int kvb, int I) {
    int krow = 4 * I + (lane >> 4);
    int c = (lane & 15) ^ (krow & 7);
    const u16* src = qkv + qb + (size_t)(kvb + krow) * 2304 + 2048 + c * 8;
    async16(src, (char*)&Kl[buf][0] + I * 1024);
  };
  auto stageV = [&](int buf, int kvb, int I) {
    int vrow = 8 * I + (lane >> 3);
    int c = (lane & 7) ^ (vrow & 7);
    const u16* src = vt + ((size_t)b * 128 + vrow) * 2048 + kvb + c * 8;
    async16(src, (char*)&Vl[buf][0] + I * 1024);
  };

  float mrow[4] = {-INFINITY, -INFINITY, -INFINITY, -INFINITY};
  float lrow[4] = {0.f, 0.f, 0.f, 0.f};
  f32x4 o[8] = {};
  const float scale = 0.08838834764831845f;
  const int ntiles = qt + 1;

#pragma unroll
  for (int ii = 0; ii < 4; ++ii) {
    stageK(0, 0, w * 4 + ii);
    stageV(0, 0, w * 4 + ii);
  }
  __syncthreads();  // drains vmcnt

  int cur = 0;
  for (int j2 = 0; j2 < ntiles; ++j2) {
    const int kvb = j2 * 64;
    const bool diag = (j2 == ntiles - 1);
    if (!diag) {
#pragma unroll
      for (int ii = 0; ii < 4; ++ii) {
        stageK(cur ^ 1, kvb + 64, w * 4 + ii);
        stageV(cur ^ 1, kvb + 64, w * 4 + ii);
      }
    }

    // ---- QK^T from LDS ----
    const char* Kb = (const char*)&Kl[cur][0];
    const char* Vb = (const char*)&Vl[cur][0];
    f32x4 sc[4] = {};
#pragma unroll
    for (int g = 0; g < 4; ++g) {
      int row = g * 16 + lr;
#pragma unroll
      for (int kc = 0; kc < 4; ++kc) {
        int byte = row * 256 + ((kc * 4 + lq) ^ (row & 7)) * 16;
        bf16x8 kf = *(const bf16x8*)(Kb + byte);
        sc[g] = __builtin_amdgcn_mfma_f32_16x16x32_bf16(qf[kc], kf, sc[g],
                                                        0, 0, 0);
      }
    }

    // ---- online softmax ----
    float vs[4][4];
    float mxr[4];
    bool need = false;
#pragma unroll
    for (int r = 0; r < 4; ++r) {
      const int qi = s0w + lq * 4 + r;
#pragma unroll
      for (int g = 0; g < 4; ++g) {
        float v = sc[g][r] * scale;
        if (diag && (kvb + g * 16 + lr > qi)) v = -INFINITY;
        vs[r][g] = v;
      }
      float mx = fmaxf(fmaxf(vs[r][0], vs[r][1]), fmaxf(vs[r][2], vs[r][3]));
#pragma unroll
      for (int d = 8; d >= 1; d >>= 1) mx = fmaxf(mx, __shfl_xor(mx, d));
      mxr[r] = mx;
      need = need || (mx > mrow[r] + 8.f);
    }
    if (__any(need)) {
#pragma unroll
      for (int r = 0; r < 4; ++r) {
        float mn = fmaxf(mrow[r], mxr[r]);
        float alpha = __expf(mrow[r] - mn);
        float rs = 0.f;
#pragma unroll
        for (int g = 0; g < 4; ++g) {
          float p = __expf(vs[r][g] - mn);
          rs += p;
          Pl[w][lq * 4 + r][g * 16 + lr] = f2bf(p);
        }
#pragma unroll
        for (int d = 8; d >= 1; d >>= 1) rs += __shfl_xor(rs, d);
        lrow[r] = lrow[r] * alpha + rs;
        mrow[r] = mn;
#pragma unroll
        for (int n = 0; n < 8; ++n) o[n][r] *= alpha;
      }
    } else {  // deferred: max grew < THR=8, skip rescale
#pragma unroll
      for (int r = 0; r < 4; ++r) {
        float rs = 0.f;
#pragma unroll
        for (int g = 0; g < 4; ++g) {
          float p = __expf(vs[r][g] - mrow[r]);
          rs += p;
          Pl[w][lq * 4 + r][g * 16 + lr] = f2bf(p);
        }
#pragma unroll
        for (int d = 8; d >= 1; d >>= 1) rs += __shfl_xor(rs, d);
        lrow[r] += rs;
      }
    }

    // ---- PV from LDS ----
    bf16x8 pa0 = *(const bf16x8*)(&Pl[w][lr][lq * 8]);
    bf16x8 pa1 = *(const bf16x8*)(&Pl[w][lr][32 + lq * 8]);
#pragma unroll
    for (int n = 0; n < 8; ++n) {
      int row = n * 16 + lr;
      int byte0 = row * 128 + (lq ^ (row & 7)) * 16;
      int byte1 = row * 128 + ((4 + lq) ^ (row & 7)) * 16;
      bf16x8 vf0 = *(const bf16x8*)(Vb + byte0);
      bf16x8 vf1 = *(const bf16x8*)(Vb + byte1);
      o[n] = __builtin_amdgcn_mfma_f32_16x16x32_bf16(pa0, vf0, o[n], 0, 0, 0);
      o[n] = __builtin_amdgcn_mfma_f32_16x16x32_bf16(pa1, vf1, o[n], 0, 0, 0);
    }

    __syncthreads();  // staged tile ready + all waves done reading cur
    cur ^= 1;
  }

#pragma unroll
  for (int r = 0; r < 4; ++r) {
    float inv = 1.f / lrow[r];
    size_t rowoff = ((size_t)b * 2048 + s0w + lq * 4 + r) * 2048 + h * 128;
#pragma unroll
    for (int n = 0; n < 8; ++n)
      ctx[rowoff + n * 16 + lr] = f2bf(o[n][r] * inv);
  }
}

extern "C" void kernel_launch(void* const* d_in, const int* in_sizes, int n_in,
                              void* d_out, int out_size, void* d_ws,
                              size_t ws_size, hipStream_t stream) {
  (void)in_sizes; (void)n_in; (void)out_size; (void)ws_size;
  const float* hs = (const float*)d_in[0];
  const float* attn_w = (const float*)d_in[1];
  const float* attn_b = (const float*)d_in[2];
  const float* proj_w = (const float*)d_in[3];
  const float* proj_b = (const float*)d_in[4];
  float* out = (float*)d_out;

  u16* hs_b = (u16*)d_ws;                      // 4096*2048
  u16* aw_b = hs_b + (size_t)4096 * 2048;      // 2304*2048
  u16* pw_b = aw_b + (size_t)2304 * 2048;      // 2048*2048
  u16* qkv_b = pw_b + (size_t)2048 * 2048;     // 4096*2304
  u16* vt_b = qkv_b + (size_t)4096 * 2304;     // 2*128*2048
  u16* ctx_b = vt_b + (size_t)2 * 128 * 2048;  // 4096*2048

  cast_bf16_kernel<<<8192, 256, 0, stream>>>(hs, hs_b, 2097152);
  cast_bf16_kernel<<<4608, 256, 0, stream>>>(attn_w, aw_b, 1179648);
  cast_bf16_kernel<<<4096, 256, 0, stream>>>(proj_w, pw_b, 1048576);

  gemm_bt<true><<<dim3(18, 32), 256, 0, stream>>>(hs_b, aw_b, attn_b, qkv_b,
                                                  4096, 2304, 2048);
  vt_kernel<<<128, 256, 0, stream>>>(qkv_b, vt_b);
  attn_kernel<<<1024, 256, 0, stream>>>(qkv_b, vt_b, ctx_b);
  gemm_bt<false><<<dim3(16, 32), 256, 0, stream>>>(ctx_b, pw_b, proj_b, out,
                                                   4096, 2048, 2048);
}

// Round 4
// 218.569 us; speedup vs baseline: 3.2232x; 1.0983x over previous
//
#include <hip/hip_runtime.h>
#include <hip/hip_bf16.h>
#include <math.h>

typedef unsigned short u16;
typedef __attribute__((ext_vector_type(8))) __bf16 bf16x8;
typedef __attribute__((ext_vector_type(4))) float f32x4;

__device__ inline u16 f2bf(float f) {
  union { float f; unsigned u; } x; x.f = f;
  unsigned r = x.u + 0x7fffu + ((x.u >> 16) & 1u);
  return (u16)(r >> 16);
}

__device__ inline unsigned cvtpk(float lo, float hi) {
  unsigned r;
  asm("v_cvt_pk_bf16_f32 %0, %1, %2" : "=v"(r) : "v"(lo), "v"(hi));
  return r;
}

__device__ inline void async16(const void* g, void* l) {
  __builtin_amdgcn_global_load_lds(
      (const __attribute__((address_space(1))) void*)g,
      (__attribute__((address_space(3))) void*)l, 16, 0, 0);
}

// ---------------- cast f32 -> bf16 (vectorized) ----------------
__global__ __launch_bounds__(256) void cast_bf16_kernel(
    const float* __restrict__ in, u16* __restrict__ out, int n4) {
  int i = blockIdx.x * 256 + threadIdx.x;
  if (i >= n4) return;
  float4 v = ((const float4*)in)[i];
  u16 o0 = f2bf(v.x), o1 = f2bf(v.y), o2 = f2bf(v.z), o3 = f2bf(v.w);
  unsigned lo = (unsigned)o0 | ((unsigned)o1 << 16);
  unsigned hi = (unsigned)o2 | ((unsigned)o3 << 16);
  ((uint2*)out)[i] = make_uint2(lo, hi);
}

// ---------------- V transpose via LDS: vt[b][d][s] = qkv[b][s][2176+d] ------
__global__ __launch_bounds__(256) void vt_kernel(
    const u16* __restrict__ qkv, u16* __restrict__ vt) {
  __shared__ u16 tile[32][136];
  const int t = threadIdx.x;
  const int b = blockIdx.x >> 6;
  const int S0 = (blockIdx.x & 63) * 32;
  const int s_l = t >> 3, dg = t & 7;
  const u16* src = qkv + ((size_t)b * 2048 + S0 + s_l) * 2304 + 2176 + dg * 16;
  *(uint4*)&tile[s_l][dg * 16] = *(const uint4*)src;
  *(uint4*)&tile[s_l][dg * 16 + 8] = *(const uint4*)(src + 8);
  __syncthreads();
  const int d = t >> 1, sh = t & 1;
  u16 buf[16];
#pragma unroll
  for (int j = 0; j < 16; ++j) buf[j] = tile[sh * 16 + j][d];
  u16* dst = vt + ((size_t)b * 128 + d) * 2048 + S0 + sh * 16;
  *(uint4*)dst = *(uint4*)&buf[0];
  *(uint4*)(dst + 8) = *(uint4*)&buf[8];
}

// ---------------- GEMM: C[M][N] = A[M][K] * W[N][K]^T + bias ----------------
template <bool BF16OUT>
__global__ __launch_bounds__(256) void gemm_bt(
    const u16* __restrict__ A, const u16* __restrict__ Bw,
    const float* __restrict__ bias, void* __restrict__ Cout,
    int M, int N, int K) {
  __shared__ u16 As[128 * 64];
  __shared__ u16 Bs[128 * 64];
  const int t = threadIdx.x;
  const int w = t >> 6;
  const int lane = t & 63;
  const int lq = lane >> 4, lr = lane & 15;
  const long brow = (long)blockIdx.y * 128;
  const long bcol = (long)blockIdx.x * 128;
  const int wr = (w >> 1) * 64, wc = (w & 1) * 64;
  f32x4 acc[4][4] = {};

  int rA[4], cA[4];
#pragma unroll
  for (int it = 0; it < 4; ++it) {
    int ci = it * 256 + t;
    rA[it] = ci >> 3;
    cA[it] = (ci & 7) ^ (rA[it] & 7);
  }

  for (int kt = 0; kt < K; kt += 64) {
#pragma unroll
    for (int it = 0; it < 4; ++it) {
      const u16* srcA = A + (brow + rA[it]) * (long)K + kt + cA[it] * 8;
      async16(srcA, (char*)As + (it * 256 + w * 64) * 16);
      const u16* srcB = Bw + (bcol + rA[it]) * (long)K + kt + cA[it] * 8;
      async16(srcB, (char*)Bs + (it * 256 + w * 64) * 16);
    }
    __syncthreads();
#pragma unroll
    for (int kb = 0; kb < 2; ++kb) {
      bf16x8 af[4], bfr[4];
#pragma unroll
      for (int m = 0; m < 4; ++m) {
        int row = wr + m * 16 + lr;
        int byte = (row * 128 + kb * 64 + lq * 16) ^ ((row & 7) << 4);
        af[m] = *(const bf16x8*)((const char*)As + byte);
      }
#pragma unroll
      for (int n = 0; n < 4; ++n) {
        int row = wc + n * 16 + lr;
        int byte = (row * 128 + kb * 64 + lq * 16) ^ ((row & 7) << 4);
        bfr[n] = *(const bf16x8*)((const char*)Bs + byte);
      }
#pragma unroll
      for (int m = 0; m < 4; ++m)
#pragma unroll
        for (int n = 0; n < 4; ++n)
          acc[m][n] = __builtin_amdgcn_mfma_f32_16x16x32_bf16(
              af[m], bfr[n], acc[m][n], 0, 0, 0);
    }
    __syncthreads();
  }

#pragma unroll
  for (int m = 0; m < 4; ++m) {
    long row0 = brow + wr + m * 16 + lq * 4;
#pragma unroll
    for (int n = 0; n < 4; ++n) {
      long col = bcol + wc + n * 16 + lr;
      float bv = bias[col];
#pragma unroll
      for (int j = 0; j < 4; ++j) {
        float v = acc[m][n][j] + bv;
        if (BF16OUT)
          ((u16*)Cout)[(row0 + j) * N + col] = f2bf(v);
        else
          ((float*)Cout)[(row0 + j) * N + col] = v;
      }
    }
  }
}

// ---------------- Flash attention (MQA, causal) ----------------
// 4 waves x 32 q-rows = 128 rows/block. Swapped QK^T (mfma(K,Q)) so each
// lane owns one q-row's 16-key strip -> 2 shuffles per row-reduce.
// K/V LDS double-buffered via global_load_lds; P via swizzled Pl round-trip.
__global__ __launch_bounds__(256, 2) void attn_kernel(
    const u16* __restrict__ qkv, const u16* __restrict__ vt,
    u16* __restrict__ ctx) {
  __shared__ u16 Kl[2][64 * 128];
  __shared__ u16 Vl[2][128 * 64];
  __shared__ u16 Pl[4][32][64];

  const int t = threadIdx.x;
  const int w = t >> 6;
  const int lane = t & 63;
  const int lq = lane >> 4, lr = lane & 15;
  const int bid = blockIdx.x;
  const int qtid = bid >> 5;
  const int qt = (qtid < 8) ? (15 - qtid) : (qtid - 8);  // heavy+light pairing
  const int hb = bid & 31;
  const int h = hb & 15;
  const int b = hb >> 4;
  const int Q0 = qt * 128;
  const int s0w = Q0 + w * 32;
  const size_t qb = (size_t)b * 2048 * 2304;

  // Q fragments: 2 frags (16 rows each) x 4 k-chunks
  bf16x8 qf[2][4];
#pragma unroll
  for (int s = 0; s < 2; ++s)
#pragma unroll
    for (int kc = 0; kc < 4; ++kc)
      qf[s][kc] = *(const bf16x8*)(qkv + qb +
                                   (size_t)(s0w + s * 16 + lr) * 2304 +
                                   h * 128 + kc * 32 + lq * 8);

  auto stageK = [&](int buf, int kvb, int I) {
    int krow = 4 * I + (lane >> 4);
    int c = (lane & 15) ^ (krow & 7);
    const u16* src = qkv + qb + (size_t)(kvb + krow) * 2304 + 2048 + c * 8;
    async16(src, (char*)&Kl[buf][0] + I * 1024);
  };
  auto stageV = [&](int buf, int kvb, int I) {
    int vrow = 8 * I + (lane >> 3);
    int c = (lane & 7) ^ (vrow & 7);
    const u16* src = vt + ((size_t)b * 128 + vrow) * 2048 + kvb + c * 8;
    async16(src, (char*)&Vl[buf][0] + I * 1024);
  };

  float mreg[2] = {-INFINITY, -INFINITY};
  float lreg[2] = {0.f, 0.f};
  f32x4 o[2][8] = {};
  const float scale2 = 0.08838834764831845f * 1.4426950408889634f;
  const int ntiles = 2 * qt + 2;
  char* pb = (char*)&Pl[w][0][0];

#pragma unroll
  for (int ii = 0; ii < 4; ++ii) {
    stageK(0, 0, w * 4 + ii);
    stageV(0, 0, w * 4 + ii);
  }
  __syncthreads();

  int cur = 0;
  for (int j2 = 0; j2 < ntiles; ++j2) {
    const int kvb = j2 * 64;
    if (j2 + 1 < ntiles) {
#pragma unroll
      for (int ii = 0; ii < 4; ++ii) {
        stageK(cur ^ 1, kvb + 64, w * 4 + ii);
        stageV(cur ^ 1, kvb + 64, w * 4 + ii);
      }
    }
    if (kvb <= s0w + 31) {  // wave-level skip of fully-masked tiles
      const char* Kb = (const char*)&Kl[cur][0];
      const char* Vb = (const char*)&Vl[cur][0];
      const bool maskT = (kvb + 63 > s0w);

      // ---- QK^T swapped: lane -> (q=lr, keys g*16+lq*4+reg) ----
      f32x4 sc[2][4] = {};
#pragma unroll
      for (int g = 0; g < 4; ++g) {
        int row = g * 16 + lr;
#pragma unroll
        for (int kc = 0; kc < 4; ++kc) {
          int byte = row * 256 + (((kc * 4 + lq) ^ (row & 7)) << 4);
          bf16x8 kf = *(const bf16x8*)(Kb + byte);
          sc[0][g] = __builtin_amdgcn_mfma_f32_16x16x32_bf16(kf, qf[0][kc],
                                                             sc[0][g], 0, 0, 0);
          sc[1][g] = __builtin_amdgcn_mfma_f32_16x16x32_bf16(kf, qf[1][kc],
                                                             sc[1][g], 0, 0, 0);
        }
      }

      // ---- softmax per frag (log2 domain) + P pack to Pl ----
#pragma unroll
      for (int s = 0; s < 2; ++s) {
        const int qrel = s0w + s * 16 + lr - kvb;
        float vv[16];
        float mx = -INFINITY;
#pragma unroll
        for (int g = 0; g < 4; ++g)
#pragma unroll
          for (int r = 0; r < 4; ++r) {
            float v = sc[s][g][r] * scale2;
            if (maskT && (g * 16 + lq * 4 + r > qrel)) v = -INFINITY;
            vv[g * 4 + r] = v;
            mx = fmaxf(mx, v);
          }
        mx = fmaxf(mx, __shfl_xor(mx, 16));
        mx = fmaxf(mx, __shfl_xor(mx, 32));
        float mn = mreg[s];
        if (__any(mx > mn + 8.f)) {  // T13 defer-rescale
          float mu = fmaxf(mn, mx);
          float alpha = exp2f(mn - mu);
          mreg[s] = mu;
          mn = mu;
          lreg[s] *= alpha;
          float a0 = __shfl(alpha, lq * 4 + 0);
          float a1 = __shfl(alpha, lq * 4 + 1);
          float a2 = __shfl(alpha, lq * 4 + 2);
          float a3 = __shfl(alpha, lq * 4 + 3);
#pragma unroll
          for (int n = 0; n < 8; ++n) {
            o[s][n][0] *= a0;
            o[s][n][1] *= a1;
            o[s][n][2] *= a2;
            o[s][n][3] *= a3;
          }
        }
        float rs = 0.f;
#pragma unroll
        for (int g = 0; g < 4; ++g)
#pragma unroll
          for (int rp = 0; rp < 2; ++rp) {
            float p0 = exp2f(vv[g * 4 + 2 * rp] - mn);
            float p1 = exp2f(vv[g * 4 + 2 * rp + 1] - mn);
            rs += p0 + p1;
            unsigned pkv = cvtpk(p0, p1);
            int byte = ((s * 16 + lr) * 128 + g * 32 + lq * 8 + rp * 4) ^
                       ((lr & 7) << 4);
            *(unsigned*)(pb + byte) = pkv;
          }
        rs += __shfl_xor(rs, 16);
        rs += __shfl_xor(rs, 32);
        lreg[s] += rs;
      }

      // ---- PV: read P fragments back, 16 vf reads feed 32 mfma ----
      bf16x8 pa[2][2];
#pragma unroll
      for (int s = 0; s < 2; ++s)
#pragma unroll
        for (int kc = 0; kc < 2; ++kc) {
          int byte = ((s * 16 + lr) * 128 + kc * 64 + lq * 16) ^
                     ((lr & 7) << 4);
          pa[s][kc] = *(const bf16x8*)(pb + byte);
        }
#pragma unroll
      for (int n = 0; n < 8; ++n) {
        int row = n * 16 + lr;
        int byte0 = row * 128 + ((lq ^ (row & 7)) << 4);
        int byte1 = row * 128 + (((4 + lq) ^ (row & 7)) << 4);
        bf16x8 vf0 = *(const bf16x8*)(Vb + byte0);
        bf16x8 vf1 = *(const bf16x8*)(Vb + byte1);
        o[0][n] = __builtin_amdgcn_mfma_f32_16x16x32_bf16(pa[0][0], vf0,
                                                          o[0][n], 0, 0, 0);
        o[0][n] = __builtin_amdgcn_mfma_f32_16x16x32_bf16(pa[0][1], vf1,
                                                          o[0][n], 0, 0, 0);
        o[1][n] = __builtin_amdgcn_mfma_f32_16x16x32_bf16(pa[1][0], vf0,
                                                          o[1][n], 0, 0, 0);
        o[1][n] = __builtin_amdgcn_mfma_f32_16x16x32_bf16(pa[1][1], vf1,
                                                          o[1][n], 0, 0, 0);
      }
    }
    __syncthreads();
    cur ^= 1;
  }

#pragma unroll
  for (int s = 0; s < 2; ++s) {
    float inv = 1.f / lreg[s];
    float iv[4];
    iv[0] = __shfl(inv, lq * 4 + 0);
    iv[1] = __shfl(inv, lq * 4 + 1);
    iv[2] = __shfl(inv, lq * 4 + 2);
    iv[3] = __shfl(inv, lq * 4 + 3);
#pragma unroll
    for (int r = 0; r < 4; ++r) {
      size_t rowoff =
          ((size_t)b * 2048 + s0w + s * 16 + lq * 4 + r) * 2048 + h * 128;
#pragma unroll
      for (int n = 0; n < 8; ++n)
        ctx[rowoff + n * 16 + lr] = f2bf(o[s][n][r] * iv[r]);
    }
  }
}

extern "C" void kernel_launch(void* const* d_in, const int* in_sizes, int n_in,
                              void* d_out, int out_size, void* d_ws,
                              size_t ws_size, hipStream_t stream) {
  (void)in_sizes; (void)n_in; (void)out_size; (void)ws_size;
  const float* hs = (const float*)d_in[0];
  const float* attn_w = (const float*)d_in[1];
  const float* attn_b = (const float*)d_in[2];
  const float* proj_w = (const float*)d_in[3];
  const float* proj_b = (const float*)d_in[4];
  float* out = (float*)d_out;

  u16* hs_b = (u16*)d_ws;                      // 4096*2048
  u16* aw_b = hs_b + (size_t)4096 * 2048;      // 2304*2048
  u16* pw_b = aw_b + (size_t)2304 * 2048;      // 2048*2048
  u16* qkv_b = pw_b + (size_t)2048 * 2048;     // 4096*2304
  u16* vt_b = qkv_b + (size_t)4096 * 2304;     // 2*128*2048
  u16* ctx_b = vt_b + (size_t)2 * 128 * 2048;  // 4096*2048

  cast_bf16_kernel<<<8192, 256, 0, stream>>>(hs, hs_b, 2097152);
  cast_bf16_kernel<<<4608, 256, 0, stream>>>(attn_w, aw_b, 1179648);
  cast_bf16_kernel<<<4096, 256, 0, stream>>>(proj_w, pw_b, 1048576);

  gemm_bt<true><<<dim3(18, 32), 256, 0, stream>>>(hs_b, aw_b, attn_b, qkv_b,
                                                  4096, 2304, 2048);
  vt_kernel<<<128, 256, 0, stream>>>(qkv_b, vt_b);
  attn_kernel<<<512, 256, 0, stream>>>(qkv_b, vt_b, ctx_b);
  gemm_bt<false><<<dim3(16, 32), 256, 0, stream>>>(ctx_b, pw_b, proj_b, out,
                                                   4096, 2048, 2048);
}